// Round 3
// baseline (529.671 us; speedup 1.0000x reference)
//
#include <hip/hip_runtime.h>
#include <hip/hip_bf16.h>
#include <stdint.h>

// Problem constants (from reference): B=4, T=2048, H=16, dk=dv=64, D=1024
#define B_  4
#define T_  2048
#define H_  16
#define DH  64
#define DM  1024

typedef unsigned short u16;
typedef float  f32x4  __attribute__((ext_vector_type(4)));
typedef u16    u16x4  __attribute__((ext_vector_type(4)));
typedef __bf16 bf16x8 __attribute__((ext_vector_type(8)));
typedef bf16x8 __attribute__((may_alias, aligned(16))) bf16x8_a;
typedef u16x4  __attribute__((may_alias, aligned(8)))  u16x4_a;

__device__ __forceinline__ void gld16(void* lds, const void* g) {
  // async global->LDS, 16B per lane; LDS dest = wave-uniform base + lane*16
  __builtin_amdgcn_global_load_lds((const __attribute__((address_space(1))) unsigned int*)g,
                                   (__attribute__((address_space(3))) unsigned int*)lds,
                                   16, 0, 0);
}
__device__ __forceinline__ u16 f2b(float f) {
  __bf16 h = (__bf16)f; return __builtin_bit_cast(unsigned short, h);
}

// ---------------------------------------------------------------------------
// X convert: f32 -> bf16, 8.4M elements, 4 per thread (exact grid, no tail)
// ---------------------------------------------------------------------------
__global__ void cvt_x(const float* __restrict__ in, u16* __restrict__ out) {
  const int i = (blockIdx.x * 256 + threadIdx.x) * 4;
  const f32x4 v = *(const f32x4*)&in[i];
  u16x4 o;
  o.x = f2b(v.x); o.y = f2b(v.y); o.z = f2b(v.z); o.w = f2b(v.w);
  *(u16x4_a*)&out[i] = o;
}

// ---------------------------------------------------------------------------
// Weight transpose+convert: WT[n][k] = bf16(W[k][n]), 1024x1024, 4 matrices
// ---------------------------------------------------------------------------
__global__ void transpose4(const float* __restrict__ Wq, const float* __restrict__ Wk,
                           const float* __restrict__ Wv, const float* __restrict__ Wo,
                           u16* __restrict__ WqT, u16* __restrict__ WkT,
                           u16* __restrict__ WvT, u16* __restrict__ WoT) {
  const float* in; u16* out;
  switch (blockIdx.z) {
    case 0: in = Wq; out = WqT; break;
    case 1: in = Wk; out = WkT; break;
    case 2: in = Wv; out = WvT; break;
    default: in = Wo; out = WoT; break;
  }
  __shared__ u16 t[32][33];
  const int bx = blockIdx.x * 32, by = blockIdx.y * 32;
  const int tx = threadIdx.x & 31, ty = threadIdx.x >> 5;  // 32 x 8
  for (int i = ty; i < 32; i += 8) t[i][tx] = f2b(in[(size_t)(by + i) * DM + bx + tx]);
  __syncthreads();
  for (int i = ty; i < 32; i += 8) out[(size_t)(bx + i) * DM + by + tx] = t[tx][i];
}

// ---------------------------------------------------------------------------
// 128x128-tile GEMM, C = A[8192x1024](bf16) * BT[1024x1024]^T(bf16) + bias(f32),
// fp32 MFMA accumulation. m97 structure: global_load_lds(16B) staging,
// 4 waves -> 2x2 wave grid, each wave 4x4 of 16x16x32 MFMA.
// mode 0: C as [B,H,T,64] bf16   (Q / K buffers)
// mode 1: C as [B,H,64,T] bf16   (V transposed)
// mode 2: Cf as [M,N] row-major f32 (final output)
// ---------------------------------------------------------------------------
__device__ __forceinline__ void gemm_bt_128(
    const u16* __restrict__ A, const u16* __restrict__ BT,
    const float* __restrict__ bias, u16* __restrict__ C, float* __restrict__ Cf,
    int mode)
{
  constexpr int K = 1024, N = 1024;
  __shared__ __attribute__((aligned(16))) u16 lA[128 * 32];
  __shared__ __attribute__((aligned(16))) u16 lB[128 * 32];
  const int tid  = threadIdx.x;
  const int lane = tid & 63;
  const int quad = lane >> 4, ln = lane & 15;
  const int wave = tid >> 6;
  const int wm = wave >> 1, wn = wave & 1;
  const int m0 = blockIdx.y * 128, n0 = blockIdx.x * 128;

  const f32x4 fz = {0.f, 0.f, 0.f, 0.f};
  f32x4 acc[4][4];
#pragma unroll
  for (int i = 0; i < 4; i++)
#pragma unroll
    for (int j = 0; j < 4; j++) acc[i][j] = fz;

  const int o0 = tid * 16;  // staging byte offset, pass 0
  for (int k0 = 0; k0 < K; k0 += 32) {
    __syncthreads();
#pragma unroll
    for (int p = 0; p < 2; ++p) {
      const int o = p * 4096 + o0;          // byte offset in 128x32 tile
      const int row = o >> 6, cole = (o & 63) >> 1;
      gld16(&lA[o >> 1], &A [(size_t)(m0 + row) * K + k0 + cole]);
      gld16(&lB[o >> 1], &BT[(size_t)(n0 + row) * K + k0 + cole]);
    }
    __syncthreads();
    bf16x8 af[4], bf[4];
#pragma unroll
    for (int i = 0; i < 4; i++)
      af[i] = *(const bf16x8_a*)&lA[(wm * 64 + i * 16 + ln) * 32 + quad * 8];
#pragma unroll
    for (int j = 0; j < 4; j++)
      bf[j] = *(const bf16x8_a*)&lB[(wn * 64 + j * 16 + ln) * 32 + quad * 8];
#pragma unroll
    for (int i = 0; i < 4; i++)
#pragma unroll
      for (int j = 0; j < 4; j++)
        acc[i][j] = __builtin_amdgcn_mfma_f32_16x16x32_bf16(af[i], bf[j], acc[i][j], 0, 0, 0);
  }

  // epilogue: D row = quad*4+reg, col = lane&15 (verified C/D layout)
#pragma unroll
  for (int j = 0; j < 4; j++) {
    const int n = n0 + wn * 64 + j * 16 + ln;
    const float bn = bias[n];
#pragma unroll
    for (int i = 0; i < 4; i++) {
      const int mb = m0 + wm * 64 + i * 16 + quad * 4;
#pragma unroll
      for (int r = 0; r < 4; r++) {
        const int m = mb + r;
        const float v = acc[i][j][r] + bn;
        if (mode == 0) {
          const int b = m >> 11, t = m & 2047, h = n >> 6, d = n & 63;
          C[((size_t)((b * H_ + h) * T_ + t)) * DH + d] = f2b(v);
        } else if (mode == 1) {
          const int b = m >> 11, t = m & 2047, h = n >> 6, d = n & 63;
          C[((size_t)((b * H_ + h) * DH + d)) * T_ + t] = f2b(v);
        } else {
          Cf[(size_t)m * N + n] = v;   // final output: f32
        }
      }
    }
  }
}

__global__ __launch_bounds__(256, 2) void qkv_gemm(
    const u16* __restrict__ X,
    const u16* __restrict__ WqT, const u16* __restrict__ WkT, const u16* __restrict__ WvT,
    const float* __restrict__ bq, const float* __restrict__ bk, const float* __restrict__ bv,
    u16* __restrict__ Qo, u16* __restrict__ Ko, u16* __restrict__ Vo)
{
  const u16 *BT; const float* bias; u16* C; int mode;
  if (blockIdx.z == 0)      { BT = WqT; bias = bq; C = Qo; mode = 0; }
  else if (blockIdx.z == 1) { BT = WkT; bias = bk; C = Ko; mode = 0; }
  else                      { BT = WvT; bias = bv; C = Vo; mode = 1; }
  gemm_bt_128(X, BT, bias, C, nullptr, mode);
}

__global__ __launch_bounds__(256, 2) void out_gemm(
    const u16* __restrict__ ctx, const u16* __restrict__ WoT,
    const float* __restrict__ bo, float* __restrict__ out)
{
  gemm_bt_128(ctx, WoT, bo, nullptr, out, 2);
}

// ---------------------------------------------------------------------------
// Flash attention, causal. One block per (128 Q-rows, b*h). 4 waves; each wave
// owns 32 Q-rows (full softmax rows -> no cross-wave reduction).
// Q,K: [B,H,T,64]; V: [B,H,64,T] (pre-transposed); ctx out: [B,T,H*64].
// Softmax in exp2 domain: z = S * 0.125 * log2(e).
// ---------------------------------------------------------------------------
__global__ __launch_bounds__(256, 2) void flash_attn(
    const u16* __restrict__ Q, const u16* __restrict__ Kg,
    const u16* __restrict__ Vt, u16* __restrict__ ctx)
{
  __shared__ __attribute__((aligned(16))) u16 lQ[128 * 64];   // [qrow][d]
  __shared__ __attribute__((aligned(16))) u16 lK[128 * 64];   // [trow][d]
  __shared__ __attribute__((aligned(16))) u16 lV[64 * 128];   // [d][t]
  __shared__ __attribute__((aligned(16))) u16 lP[128 * 128];  // [qrow][t]

  const int bh = blockIdx.y;            // b*16 + h
  const int b  = bh >> 4, h = bh & 15;
  const int qi = blockIdx.x;
  const int q0 = qi * 128;
  const int tid = threadIdx.x;
  const int lane = tid & 63, wave = tid >> 6;
  const int quad = lane >> 4, ln = lane & 15;

  const u16* Qbh = Q  + (size_t)bh * T_ * DH;
  const u16* Kbh = Kg + (size_t)bh * T_ * DH;
  const u16* Vbh = Vt + (size_t)bh * DH * T_;

  // stage Q tile (16KB, contiguous in global)
#pragma unroll
  for (int p = 0; p < 4; ++p) {
    const int o = p * 4096 + tid * 16;
    gld16(&lQ[o >> 1], &Qbh[(size_t)q0 * DH + (o >> 1)]);
  }

  const f32x4 fz = {0.f, 0.f, 0.f, 0.f};
  float m_[2][4], l_[2][4];
  f32x4 accO[2][4];
#pragma unroll
  for (int mt = 0; mt < 2; mt++)
#pragma unroll
    for (int r = 0; r < 4; r++) { m_[mt][r] = -INFINITY; l_[mt][r] = 0.f; }
#pragma unroll
  for (int mt = 0; mt < 2; mt++)
#pragma unroll
    for (int j = 0; j < 4; j++) accO[mt][j] = fz;

  const float sc = 0.1803368801111144f;  // 0.125 * log2(e)

  for (int kt = 0; kt <= qi; ++kt) {
    const int t0 = kt * 128;
    __syncthreads();   // previous iter done reading lK/lV
#pragma unroll
    for (int p = 0; p < 4; ++p) {
      const int o = p * 4096 + tid * 16;
      gld16(&lK[o >> 1], &Kbh[(size_t)t0 * DH + (o >> 1)]);
    }
#pragma unroll
    for (int p = 0; p < 4; ++p) {
      const int o = p * 4096 + tid * 16;          // V tile: 64 rows x 256B
      const int row = o >> 8, cole = (o & 255) >> 1;
      gld16(&lV[o >> 1], &Vbh[(size_t)row * T_ + t0 + cole]);
    }
    __syncthreads();

    // S = Q K^T for rows [wave*32, wave*32+32), cols [0,128)
    f32x4 s[2][8];
#pragma unroll
    for (int mt = 0; mt < 2; mt++)
#pragma unroll
      for (int j = 0; j < 8; j++) s[mt][j] = fz;
#pragma unroll
    for (int ks = 0; ks < 2; ++ks) {
      bf16x8 aq[2], bk8[8];
#pragma unroll
      for (int mt = 0; mt < 2; mt++)
        aq[mt] = *(const bf16x8_a*)&lQ[(wave * 32 + mt * 16 + ln) * 64 + ks * 32 + quad * 8];
#pragma unroll
      for (int j = 0; j < 8; j++)
        bk8[j] = *(const bf16x8_a*)&lK[(j * 16 + ln) * 64 + ks * 32 + quad * 8];
#pragma unroll
      for (int mt = 0; mt < 2; mt++)
#pragma unroll
        for (int j = 0; j < 8; j++)
          s[mt][j] = __builtin_amdgcn_mfma_f32_16x16x32_bf16(aq[mt], bk8[j], s[mt][j], 0, 0, 0);
    }

    const bool diag = (kt == qi);
#pragma unroll
    for (int mt = 0; mt < 2; mt++) {
      float alpha[4];
#pragma unroll
      for (int r = 0; r < 4; r++) {
        const int qrow = q0 + wave * 32 + mt * 16 + quad * 4 + r;
        float vmax = -INFINITY;
#pragma unroll
        for (int j = 0; j < 8; j++) {
          float z = s[mt][j][r] * sc;
          if (diag && (t0 + j * 16 + ln) > qrow) z = -INFINITY;
          s[mt][j][r] = z;
          vmax = fmaxf(vmax, z);
        }
#pragma unroll
        for (int d = 1; d < 16; d <<= 1) vmax = fmaxf(vmax, __shfl_xor(vmax, d));
        const float mnew = fmaxf(m_[mt][r], vmax);
        float sum = 0.f;
#pragma unroll
        for (int j = 0; j < 8; j++) {
          const float p = exp2f(s[mt][j][r] - mnew);
          s[mt][j][r] = p;
          sum += p;
        }
#pragma unroll
        for (int d = 1; d < 16; d <<= 1) sum += __shfl_xor(sum, d);
        alpha[r] = exp2f(m_[mt][r] - mnew);
        l_[mt][r] = l_[mt][r] * alpha[r] + sum;
        m_[mt][r] = mnew;
      }
      // rescale O accumulator
#pragma unroll
      for (int j2 = 0; j2 < 4; j2++)
#pragma unroll
        for (int r = 0; r < 4; r++) accO[mt][j2][r] *= alpha[r];
      // write P (C-layout -> [q][t] LDS; scalar b16 stores)
#pragma unroll
      for (int j = 0; j < 8; j++)
#pragma unroll
        for (int r = 0; r < 4; r++)
          lP[(wave * 32 + mt * 16 + quad * 4 + r) * 128 + j * 16 + ln] = f2b(s[mt][j][r]);
    }

    // O += P V  (K-dim = 128, per-wave rows only -> no barrier needed on lP)
#pragma unroll
    for (int ks = 0; ks < 4; ++ks) {
      bf16x8 ap[2], bv8[4];
#pragma unroll
      for (int mt = 0; mt < 2; mt++)
        ap[mt] = *(const bf16x8_a*)&lP[(wave * 32 + mt * 16 + ln) * 128 + ks * 32 + quad * 8];
#pragma unroll
      for (int j2 = 0; j2 < 4; j2++)
        bv8[j2] = *(const bf16x8_a*)&lV[(j2 * 16 + ln) * 128 + ks * 32 + quad * 8];
#pragma unroll
      for (int mt = 0; mt < 2; mt++)
#pragma unroll
        for (int j2 = 0; j2 < 4; j2++)
          accO[mt][j2] = __builtin_amdgcn_mfma_f32_16x16x32_bf16(ap[mt], bv8[j2], accO[mt][j2], 0, 0, 0);
    }
  }

  // epilogue: ctx[b][q][h*64+d] = O / l
#pragma unroll
  for (int mt = 0; mt < 2; mt++)
#pragma unroll
    for (int r = 0; r < 4; r++) {
      const int qrow = q0 + wave * 32 + mt * 16 + quad * 4 + r;
      const float inv = 1.0f / l_[mt][r];
#pragma unroll
      for (int j2 = 0; j2 < 4; j2++) {
        const int d = j2 * 16 + ln;
        ctx[((size_t)(b * T_ + qrow)) * DM + h * DH + d] = f2b(accO[mt][j2][r] * inv);
      }
    }
}

// ---------------------------------------------------------------------------
extern "C" void kernel_launch(void* const* d_in, const int* in_sizes, int n_in,
                              void* d_out, int out_size, void* d_ws, size_t ws_size,
                              hipStream_t stream) {
  (void)in_sizes; (void)n_in; (void)out_size; (void)ws_size;
  const float* X  = (const float*)d_in[0];   // f32 inputs per reference dtypes
  // d_in[1] = causal mask (structure known; unused)
  const float* Wq = (const float*)d_in[2];
  const float* bq = (const float*)d_in[3];
  const float* Wk = (const float*)d_in[4];
  const float* bk = (const float*)d_in[5];
  const float* Wv = (const float*)d_in[6];
  const float* bv = (const float*)d_in[7];
  const float* Wo = (const float*)d_in[8];
  const float* bo = (const float*)d_in[9];
  float* out = (float*)d_out;                // f32 output per reference dtype

  char* ws = (char*)d_ws;
  u16* WqT = (u16*)(ws + (0ull  << 20));   // [1024,1024] bf16 (transposed)
  u16* WkT = (u16*)(ws + (2ull  << 20));
  u16* WvT = (u16*)(ws + (4ull  << 20));
  u16* WoT = (u16*)(ws + (6ull  << 20));
  u16* Xb  = (u16*)(ws + (8ull  << 20));   // [8192,1024] bf16
  u16* Qb  = (u16*)(ws + (24ull << 20));   // [B,H,T,64]
  u16* Kb  = (u16*)(ws + (40ull << 20));   // [B,H,T,64]
  u16* Vtb = (u16*)(ws + (56ull << 20));   // [B,H,64,T]
  u16* ctx = (u16*)(ws + (72ull << 20));   // [B,T,1024]

  cvt_x<<<8192, 256, 0, stream>>>(X, Xb);  // 8.4M elems, 4/thread
  transpose4<<<dim3(32, 32, 4), 256, 0, stream>>>(Wq, Wk, Wv, Wo, WqT, WkT, WvT, WoT);
  qkv_gemm<<<dim3(8, 64, 3), 256, 0, stream>>>(Xb, WqT, WkT, WvT, bq, bk, bv, Qb, Kb, Vtb);
  flash_attn<<<dim3(16, 64), 256, 0, stream>>>(Qb, Kb, Vtb, ctx);
  out_gemm<<<dim3(8, 64), 256, 0, stream>>>(ctx, WoT, bo, out);
}

// Round 4
// 403.470 us; speedup vs baseline: 1.3128x; 1.3128x over previous
//
#include <hip/hip_runtime.h>
#include <hip/hip_bf16.h>
#include <stdint.h>

// Problem constants (from reference): B=4, T=2048, H=16, dk=dv=64, D=1024
#define B_  4
#define T_  2048
#define H_  16
#define DH  64
#define DM  1024

typedef unsigned short u16;
typedef float  f32x4  __attribute__((ext_vector_type(4)));
typedef u16    u16x4  __attribute__((ext_vector_type(4)));
typedef __bf16 bf16x8 __attribute__((ext_vector_type(8)));
typedef bf16x8 __attribute__((may_alias, aligned(16))) bf16x8_a;
typedef u16x4  __attribute__((may_alias, aligned(8)))  u16x4_a;

__device__ __forceinline__ void gld16(void* lds, const void* g) {
  // async global->LDS, 16B per lane; LDS dest = wave-uniform base + lane*16
  __builtin_amdgcn_global_load_lds((const __attribute__((address_space(1))) unsigned int*)g,
                                   (__attribute__((address_space(3))) unsigned int*)lds,
                                   16, 0, 0);
}
__device__ __forceinline__ u16 f2b(float f) {
  __bf16 h = (__bf16)f; return __builtin_bit_cast(unsigned short, h);
}

// ---------------------------------------------------------------------------
// X convert: f32 -> bf16, 8.4M elements, 4 per thread (exact grid, no tail)
// ---------------------------------------------------------------------------
__global__ void cvt_x(const float* __restrict__ in, u16* __restrict__ out) {
  const int i = (blockIdx.x * 256 + threadIdx.x) * 4;
  const f32x4 v = *(const f32x4*)&in[i];
  u16x4 o;
  o.x = f2b(v.x); o.y = f2b(v.y); o.z = f2b(v.z); o.w = f2b(v.w);
  *(u16x4_a*)&out[i] = o;
}

// ---------------------------------------------------------------------------
// Weight transpose+convert: WT[n][k] = bf16(W[k][n]), 1024x1024, 4 matrices
// ---------------------------------------------------------------------------
__global__ void transpose4(const float* __restrict__ Wq, const float* __restrict__ Wk,
                           const float* __restrict__ Wv, const float* __restrict__ Wo,
                           u16* __restrict__ WqT, u16* __restrict__ WkT,
                           u16* __restrict__ WvT, u16* __restrict__ WoT) {
  const float* in; u16* out;
  switch (blockIdx.z) {
    case 0: in = Wq; out = WqT; break;
    case 1: in = Wk; out = WkT; break;
    case 2: in = Wv; out = WvT; break;
    default: in = Wo; out = WoT; break;
  }
  __shared__ u16 t[32][33];
  const int bx = blockIdx.x * 32, by = blockIdx.y * 32;
  const int tx = threadIdx.x & 31, ty = threadIdx.x >> 5;  // 32 x 8
  for (int i = ty; i < 32; i += 8) t[i][tx] = f2b(in[(size_t)(by + i) * DM + bx + tx]);
  __syncthreads();
  for (int i = ty; i < 32; i += 8) out[(size_t)(bx + i) * DM + by + tx] = t[tx][i];
}

// ---------------------------------------------------------------------------
// V transpose: [B,H,T,64] -> [B,H,64,T], 64x64 LDS tiles, coalesced both ways
// ---------------------------------------------------------------------------
__global__ void transpose_v(const u16* __restrict__ in, u16* __restrict__ out) {
  __shared__ u16 t[64][65];
  const int bh = blockIdx.y, t0 = blockIdx.x * 64;
  const int tx = threadIdx.x & 63, ty = threadIdx.x >> 6;  // 64 x 4
  const u16* ib = in  + (size_t)bh * T_ * DH;
  u16*       ob = out + (size_t)bh * DH * T_;
  for (int i = ty; i < 64; i += 4) t[i][tx] = ib[(size_t)(t0 + i) * DH + tx];
  __syncthreads();
  for (int i = ty; i < 64; i += 4) ob[(size_t)i * T_ + t0 + tx] = t[tx][i];
}

// ---------------------------------------------------------------------------
// 128x128-tile GEMM, C = A[8192x1024](bf16) * BT[1024x1024]^T(bf16) + bias(f32),
// fp32 MFMA accumulation. m97 structure: global_load_lds(16B) staging,
// 4 waves -> 2x2 wave grid, each wave 4x4 of 16x16x32 MFMA.
// mode 0: C as [B,H,T,64] bf16   (Q / K / V buffers)
// mode 2: Cf as [M,N] row-major f32 (final output)
// ---------------------------------------------------------------------------
__device__ __forceinline__ void gemm_bt_128(
    const u16* __restrict__ A, const u16* __restrict__ BT,
    const float* __restrict__ bias, u16* __restrict__ C, float* __restrict__ Cf,
    int mode)
{
  constexpr int K = 1024, N = 1024;
  __shared__ __attribute__((aligned(16))) u16 lA[128 * 32];
  __shared__ __attribute__((aligned(16))) u16 lB[128 * 32];
  const int tid  = threadIdx.x;
  const int lane = tid & 63;
  const int quad = lane >> 4, ln = lane & 15;
  const int wave = tid >> 6;
  const int wm = wave >> 1, wn = wave & 1;
  const int m0 = blockIdx.y * 128, n0 = blockIdx.x * 128;

  const f32x4 fz = {0.f, 0.f, 0.f, 0.f};
  f32x4 acc[4][4];
#pragma unroll
  for (int i = 0; i < 4; i++)
#pragma unroll
    for (int j = 0; j < 4; j++) acc[i][j] = fz;

  const int o0 = tid * 16;  // staging byte offset, pass 0
  for (int k0 = 0; k0 < K; k0 += 32) {
    __syncthreads();
#pragma unroll
    for (int p = 0; p < 2; ++p) {
      const int o = p * 4096 + o0;          // byte offset in 128x32 tile
      const int row = o >> 6, cole = (o & 63) >> 1;
      gld16(&lA[o >> 1], &A [(size_t)(m0 + row) * K + k0 + cole]);
      gld16(&lB[o >> 1], &BT[(size_t)(n0 + row) * K + k0 + cole]);
    }
    __syncthreads();
    bf16x8 af[4], bf[4];
#pragma unroll
    for (int i = 0; i < 4; i++)
      af[i] = *(const bf16x8_a*)&lA[(wm * 64 + i * 16 + ln) * 32 + quad * 8];
#pragma unroll
    for (int j = 0; j < 4; j++)
      bf[j] = *(const bf16x8_a*)&lB[(wn * 64 + j * 16 + ln) * 32 + quad * 8];
#pragma unroll
    for (int i = 0; i < 4; i++)
#pragma unroll
      for (int j = 0; j < 4; j++)
        acc[i][j] = __builtin_amdgcn_mfma_f32_16x16x32_bf16(af[i], bf[j], acc[i][j], 0, 0, 0);
  }

  // epilogue: D row = quad*4+reg, col = lane&15 (verified C/D layout)
#pragma unroll
  for (int j = 0; j < 4; j++) {
    const int n = n0 + wn * 64 + j * 16 + ln;
    const float bn = bias[n];
#pragma unroll
    for (int i = 0; i < 4; i++) {
      const int mb = m0 + wm * 64 + i * 16 + quad * 4;
#pragma unroll
      for (int r = 0; r < 4; r++) {
        const int m = mb + r;
        const float v = acc[i][j][r] + bn;
        if (mode == 0) {
          const int b = m >> 11, t = m & 2047, h = n >> 6, d = n & 63;
          C[((size_t)((b * H_ + h) * T_ + t)) * DH + d] = f2b(v);
        } else {
          Cf[(size_t)m * N + n] = v;   // final output: f32
        }
      }
    }
  }
}

__global__ __launch_bounds__(256, 2) void qkv_gemm(
    const u16* __restrict__ X,
    const u16* __restrict__ WqT, const u16* __restrict__ WkT, const u16* __restrict__ WvT,
    const float* __restrict__ bq, const float* __restrict__ bk, const float* __restrict__ bv,
    u16* __restrict__ Qo, u16* __restrict__ Ko, u16* __restrict__ Vo)
{
  const u16 *BT; const float* bias; u16* C;
  if (blockIdx.z == 0)      { BT = WqT; bias = bq; C = Qo; }
  else if (blockIdx.z == 1) { BT = WkT; bias = bk; C = Ko; }
  else                      { BT = WvT; bias = bv; C = Vo; }
  gemm_bt_128(X, BT, bias, C, nullptr, 0);
}

__global__ __launch_bounds__(256, 2) void out_gemm(
    const u16* __restrict__ ctx, const u16* __restrict__ WoT,
    const float* __restrict__ bo, float* __restrict__ out)
{
  gemm_bt_128(ctx, WoT, bo, nullptr, out, 2);
}

// ---------------------------------------------------------------------------
// Flash attention, causal. One block per (128 Q-rows, b*h). 8 waves (512 thr);
// each wave owns ONE 16-row Q-strip (full softmax rows, no cross-wave redux).
// Q,K: [B,H,T,64]; V: [B,H,64,T] (pre-transposed); ctx out: [B,T,H*64].
// Grid: (bh=64, 16) with qi = 15 - blockIdx.y  => LPT dispatch (longest first).
// Softmax in exp2 domain: z = S * 0.125 * log2(e).
// ---------------------------------------------------------------------------
__global__ __launch_bounds__(512, 4) void flash_attn(
    const u16* __restrict__ Q, const u16* __restrict__ Kg,
    const u16* __restrict__ Vt, u16* __restrict__ ctx)
{
  __shared__ __attribute__((aligned(16))) u16 lQ[128 * 64];   // [qrow][d]   16KB
  __shared__ __attribute__((aligned(16))) u16 lK[128 * 64];   // [trow][d]   16KB
  __shared__ __attribute__((aligned(16))) u16 lV[64 * 128];   // [d][t]      16KB
  __shared__ __attribute__((aligned(16))) u16 lP[128 * 128];  // [qrow][t]   32KB

  const int bh = blockIdx.x;            // b*16 + h
  const int b  = bh >> 4, h = bh & 15;
  const int qi = 15 - blockIdx.y;       // LPT: longest blocks dispatch first
  const int q0 = qi * 128;
  const int tid = threadIdx.x;
  const int lane = tid & 63, wave = tid >> 6;      // 8 waves
  const int quad = lane >> 4, ln = lane & 15;
  const int w16 = wave * 16;            // this wave's Q-strip base row

  const u16* Qbh = Q  + (size_t)bh * T_ * DH;
  const u16* Kbh = Kg + (size_t)bh * T_ * DH;
  const u16* Vbh = Vt + (size_t)bh * DH * T_;

  // stage Q tile (16KB contiguous; 512 lanes x 16B = 8KB per pass)
#pragma unroll
  for (int p = 0; p < 2; ++p) {
    const int o = p * 8192 + tid * 16;
    gld16(&lQ[o >> 1], &Qbh[(size_t)q0 * DH + (o >> 1)]);
  }

  const f32x4 fz = {0.f, 0.f, 0.f, 0.f};
  float m_[4], l_[4];
  f32x4 accO[4];
#pragma unroll
  for (int r = 0; r < 4; r++) { m_[r] = -INFINITY; l_[r] = 0.f; }
#pragma unroll
  for (int j = 0; j < 4; j++) accO[j] = fz;

  const float sc = 0.1803368801111144f;  // 0.125 * log2(e)

  for (int kt = 0; kt <= qi; ++kt) {
    const int t0 = kt * 128;
    __syncthreads();   // previous iter done reading lK/lV
#pragma unroll
    for (int p = 0; p < 2; ++p) {
      const int o = p * 8192 + tid * 16;
      gld16(&lK[o >> 1], &Kbh[(size_t)t0 * DH + (o >> 1)]);
    }
#pragma unroll
    for (int p = 0; p < 2; ++p) {
      const int o = p * 8192 + tid * 16;          // V tile: 64 rows x 256B
      const int row = o >> 8, cole = (o & 255) >> 1;
      gld16(&lV[o >> 1], &Vbh[(size_t)row * T_ + t0 + cole]);
    }
    __syncthreads();

    // S = Q K^T for this wave's 16 rows, cols [0,128)
    f32x4 s[8];
#pragma unroll
    for (int j = 0; j < 8; j++) s[j] = fz;
#pragma unroll
    for (int ks = 0; ks < 2; ++ks) {
      bf16x8 aq, bk8[8];
      aq = *(const bf16x8_a*)&lQ[(w16 + ln) * 64 + ks * 32 + quad * 8];
#pragma unroll
      for (int j = 0; j < 8; j++)
        bk8[j] = *(const bf16x8_a*)&lK[(j * 16 + ln) * 64 + ks * 32 + quad * 8];
#pragma unroll
      for (int j = 0; j < 8; j++)
        s[j] = __builtin_amdgcn_mfma_f32_16x16x32_bf16(aq, bk8[j], s[j], 0, 0, 0);
    }

    const bool diag = (kt == qi);
    float alpha[4];
#pragma unroll
    for (int r = 0; r < 4; r++) {
      const int qrow = q0 + w16 + quad * 4 + r;
      float vmax = -INFINITY;
#pragma unroll
      for (int j = 0; j < 8; j++) {
        float z = s[j][r] * sc;
        if (diag && (t0 + j * 16 + ln) > qrow) z = -INFINITY;
        s[j][r] = z;
        vmax = fmaxf(vmax, z);
      }
#pragma unroll
      for (int d = 1; d < 16; d <<= 1) vmax = fmaxf(vmax, __shfl_xor(vmax, d));
      const float mnew = fmaxf(m_[r], vmax);
      float sum = 0.f;
#pragma unroll
      for (int j = 0; j < 8; j++) {
        const float p = exp2f(s[j][r] - mnew);
        s[j][r] = p;
        sum += p;
      }
#pragma unroll
      for (int d = 1; d < 16; d <<= 1) sum += __shfl_xor(sum, d);
      alpha[r] = exp2f(m_[r] - mnew);
      l_[r] = l_[r] * alpha[r] + sum;
      m_[r] = mnew;
    }
    // rescale O accumulator
#pragma unroll
    for (int j2 = 0; j2 < 4; j2++)
#pragma unroll
      for (int r = 0; r < 4; r++) accO[j2][r] *= alpha[r];
    // write P (C-layout -> [q][t] LDS; scalar b16 stores)
#pragma unroll
    for (int j = 0; j < 8; j++)
#pragma unroll
      for (int r = 0; r < 4; r++)
        lP[(w16 + quad * 4 + r) * 128 + j * 16 + ln] = f2b(s[j][r]);

    // O += P V  (K-dim = 128; wave reads only its own lP rows -> no barrier)
#pragma unroll
    for (int ks = 0; ks < 4; ++ks) {
      bf16x8 ap, bv8[4];
      ap = *(const bf16x8_a*)&lP[(w16 + ln) * 128 + ks * 32 + quad * 8];
#pragma unroll
      for (int j2 = 0; j2 < 4; j2++)
        bv8[j2] = *(const bf16x8_a*)&lV[(j2 * 16 + ln) * 128 + ks * 32 + quad * 8];
#pragma unroll
      for (int j2 = 0; j2 < 4; j2++)
        accO[j2] = __builtin_amdgcn_mfma_f32_16x16x32_bf16(ap, bv8[j2], accO[j2], 0, 0, 0);
    }
  }

  // epilogue: ctx[b][q][h*64+d] = O / l
#pragma unroll
  for (int r = 0; r < 4; r++) {
    const int qrow = q0 + w16 + quad * 4 + r;
    const float inv = 1.0f / l_[r];
#pragma unroll
    for (int j2 = 0; j2 < 4; j2++) {
      const int d = j2 * 16 + ln;
      ctx[((size_t)(b * T_ + qrow)) * DM + h * DH + d] = f2b(accO[j2][r] * inv);
    }
  }
}

// ---------------------------------------------------------------------------
extern "C" void kernel_launch(void* const* d_in, const int* in_sizes, int n_in,
                              void* d_out, int out_size, void* d_ws, size_t ws_size,
                              hipStream_t stream) {
  (void)in_sizes; (void)n_in; (void)out_size; (void)ws_size;
  const float* X  = (const float*)d_in[0];   // f32 inputs per reference dtypes
  // d_in[1] = causal mask (structure known; unused)
  const float* Wq = (const float*)d_in[2];
  const float* bq = (const float*)d_in[3];
  const float* Wk = (const float*)d_in[4];
  const float* bk = (const float*)d_in[5];
  const float* Wv = (const float*)d_in[6];
  const float* bv = (const float*)d_in[7];
  const float* Wo = (const float*)d_in[8];
  const float* bo = (const float*)d_in[9];
  float* out = (float*)d_out;                // f32 output per reference dtype

  char* ws = (char*)d_ws;
  u16* WqT = (u16*)(ws + (0ull  << 20));   // [1024,1024] bf16 (transposed)
  u16* WkT = (u16*)(ws + (2ull  << 20));
  u16* WvT = (u16*)(ws + (4ull  << 20));
  u16* WoT = (u16*)(ws + (6ull  << 20));
  u16* Xb  = (u16*)(ws + (8ull  << 20));   // [8192,1024] bf16
  u16* Qb  = (u16*)(ws + (24ull << 20));   // [B,H,T,64]
  u16* Kb  = (u16*)(ws + (40ull << 20));   // [B,H,T,64]
  u16* Vb  = (u16*)(ws + (56ull << 20));   // [B,H,T,64]
  u16* Vtb = (u16*)(ws + (72ull << 20));   // [B,H,64,T]
  u16* ctx = (u16*)(ws + (88ull << 20));   // [B,T,1024]

  cvt_x<<<8192, 256, 0, stream>>>(X, Xb);  // 8.4M elems, 4/thread
  transpose4<<<dim3(32, 32, 4), 256, 0, stream>>>(Wq, Wk, Wv, Wo, WqT, WkT, WvT, WoT);
  qkv_gemm<<<dim3(8, 64, 3), 256, 0, stream>>>(Xb, WqT, WkT, WvT, bq, bk, bv, Qb, Kb, Vb);
  transpose_v<<<dim3(32, 64), 256, 0, stream>>>(Vb, Vtb);
  flash_attn<<<dim3(64, 16), 512, 0, stream>>>(Qb, Kb, Vtb, ctx);
  out_gemm<<<dim3(8, 64), 256, 0, stream>>>(ctx, WoT, bo, out);
}